// Round 15
// baseline (99.659 us; speedup 1.0000x reference)
//
#include <hip/hip_runtime.h>
#include <stdint.h>

#define HEADS 12
#define DMODEL 768
#define BATCH 2
#define SEQ 2048
#define BS (BATCH * SEQ)
#define HD 64

typedef float f32x4 __attribute__((ext_vector_type(4)));
typedef __bf16 bf16x8 __attribute__((ext_vector_type(8)));
typedef short s16x4 __attribute__((ext_vector_type(4)));
typedef unsigned short u16;
typedef u16 u16x8 __attribute__((ext_vector_type(8)));
typedef u16 u16x4 __attribute__((ext_vector_type(4)));

__device__ __forceinline__ u16 f2b(float f) {
    return __builtin_bit_cast(u16, (__bf16)f);
}

__device__ __forceinline__ void gld_lds16(const void* g, void* l) {
    __builtin_amdgcn_global_load_lds(
        (__attribute__((address_space(1))) void*)(g),
        (__attribute__((address_space(3))) void*)(l), 16, 0, 0);
}
__device__ __forceinline__ void gld_lds4(const void* g, void* l) {
    __builtin_amdgcn_global_load_lds(
        (__attribute__((address_space(1))) void*)(g),
        (__attribute__((address_space(3))) void*)(l), 4, 0, 0);
}

// ---------------- prep: fp32 -> bf16 (vectorized) ----------------
__global__ __launch_bounds__(256) void cvt_x(
    const float* __restrict__ q, const float* __restrict__ k, const float* __restrict__ v,
    u16* __restrict__ xq, u16* __restrict__ xk, u16* __restrict__ xv) {
    int z = blockIdx.z;
    const float* s = (z == 0) ? q : (z == 1) ? k : v;
    u16* d = (z == 0) ? xq : (z == 1) ? xk : xv;
    size_t i = (size_t)blockIdx.x * blockDim.x + threadIdx.x;
    const float4* s4 = (const float4*)s;
    float4 a = s4[2 * i], b = s4[2 * i + 1];
    u16x8 o;
    o[0] = f2b(a.x); o[1] = f2b(a.y); o[2] = f2b(a.z); o[3] = f2b(a.w);
    o[4] = f2b(b.x); o[5] = f2b(b.y); o[6] = f2b(b.z); o[7] = f2b(b.w);
    *(u16x8*)(d + 8 * i) = o;
}

// ---------------- prep: W -> W^T bf16 ----------------
__global__ void cvt_wt(const float* __restrict__ wq, const float* __restrict__ wk,
                       const float* __restrict__ wv,
                       u16* __restrict__ tq, u16* __restrict__ tk, u16* __restrict__ tv) {
    int z = blockIdx.z;
    const float* w = (z == 0) ? wq : (z == 1) ? wk : wv;
    u16* t = (z == 0) ? tq : (z == 1) ? tk : tv;
    __shared__ float tile[32][33];
    int tx = threadIdx.x, ty = threadIdx.y;
    int kb = blockIdx.y * 32, nb = blockIdx.x * 32;
    for (int r = 0; r < 32; r += 8)
        tile[ty + r][tx] = w[(size_t)(kb + ty + r) * DMODEL + nb + tx];
    __syncthreads();
    for (int r = 0; r < 32; r += 8)
        t[(size_t)(nb + ty + r) * DMODEL + kb + tx] = f2b(tile[tx][ty + r]);
}

// ---------------- projection GEMM: C[m][n] = X[m][k] * W[k][n] ----------------
// z=0 -> qw [B,H,S,64] PRE-SCALED by 0.125*log2(e); z=1 -> kw [B,H,S,64];
// z=2 -> vt [B,H,64,S] via swapped-operand MFMA (C^T fragments, coalesced stores)
__global__ __launch_bounds__(256, 2) void proj_gemm(
    const u16* __restrict__ xq, const u16* __restrict__ xk, const u16* __restrict__ xv,
    const u16* __restrict__ tq, const u16* __restrict__ tk, const u16* __restrict__ tv,
    u16* __restrict__ oq, u16* __restrict__ ok, u16* __restrict__ ov) {
    const int z = blockIdx.z;
    const u16* X  = (z == 0) ? xq : (z == 1) ? xk : xv;
    const u16* WT = (z == 0) ? tq : (z == 1) ? tk : tv;
    u16* Out      = (z == 0) ? oq : (z == 1) ? ok : ov;

    __shared__ u16 As[128 * 64];
    __shared__ u16 Bs[128 * 64];

    const int tid = threadIdx.x;
    const int lane = tid & 63, w = tid >> 6;
    const int wm = w >> 1, wn = w & 1;
    const int m0 = blockIdx.x * 128, n0 = blockIdx.y * 128;

    f32x4 acc[4][4] = {};

    for (int kt = 0; kt < DMODEL / 64; ++kt) {
#pragma unroll
        for (int p = 0; p < 4; ++p) {
            int o = (p * 4 + w) * 1024 + lane * 16;
            int row = o >> 7;
            int col = (o & 127) ^ ((row & 7) << 4);
            gld_lds16((const char*)X + (size_t)(m0 + row) * (DMODEL * 2) + kt * 128 + col,
                      (char*)As + (p * 4 + w) * 1024);
            gld_lds16((const char*)WT + (size_t)(n0 + row) * (DMODEL * 2) + kt * 128 + col,
                      (char*)Bs + (p * 4 + w) * 1024);
        }
        __syncthreads();
#pragma unroll
        for (int kk = 0; kk < 2; ++kk) {
            bf16x8 af[4], bfr[4];
#pragma unroll
            for (int mi = 0; mi < 4; ++mi) {
                int row = wm * 64 + mi * 16 + (lane & 15);
                int col = (kk * 64 + ((lane >> 4) << 4)) ^ ((row & 7) << 4);
                af[mi] = *(const bf16x8*)((const char*)As + row * 128 + col);
            }
#pragma unroll
            for (int ni = 0; ni < 4; ++ni) {
                int row = wn * 64 + ni * 16 + (lane & 15);
                int col = (kk * 64 + ((lane >> 4) << 4)) ^ ((row & 7) << 4);
                bfr[ni] = *(const bf16x8*)((const char*)Bs + row * 128 + col);
            }
            if (z == 2) {
#pragma unroll
                for (int mi = 0; mi < 4; ++mi)
#pragma unroll
                    for (int ni = 0; ni < 4; ++ni)
                        acc[mi][ni] = __builtin_amdgcn_mfma_f32_16x16x32_bf16(
                            bfr[ni], af[mi], acc[mi][ni], 0, 0, 0);   // C^T fragments
            } else {
#pragma unroll
                for (int mi = 0; mi < 4; ++mi)
#pragma unroll
                    for (int ni = 0; ni < 4; ++ni)
                        acc[mi][ni] = __builtin_amdgcn_mfma_f32_16x16x32_bf16(
                            af[mi], bfr[ni], acc[mi][ni], 0, 0, 0);
            }
        }
        __syncthreads();
    }

    if (z == 2) {
        const int m = m0 + wm * 64 + (tid & 15);
        const int b = m >> 11;
#pragma unroll
        for (int mi = 0; mi < 4; ++mi) {
            int s = ((m + mi * 16) & 2047);
#pragma unroll
            for (int ni = 0; ni < 4; ++ni) {
                int nb2 = n0 + wn * 64 + ni * 16 + (((tid & 63) >> 4) << 2);
#pragma unroll
                for (int r = 0; r < 4; ++r) {
                    int n = nb2 + r;
                    int h = n >> 6, dd = n & 63;
                    Out[((size_t)(b * HEADS + h) * HD + dd) * SEQ + s] =
                        f2b(acc[mi][ni][r]);
                }
            }
        }
    } else {
        const float mul = (z == 0) ? 0.125f * 1.44269504f : 1.0f;
#pragma unroll
        for (int mi = 0; mi < 4; ++mi) {
            int mb = m0 + wm * 64 + mi * 16 + (((tid & 63) >> 4) << 2);
#pragma unroll
            for (int ni = 0; ni < 4; ++ni) {
                int n = n0 + wn * 64 + ni * 16 + (tid & 15);
                int h = n >> 6, dd = n & 63;
#pragma unroll
                for (int r = 0; r < 4; ++r) {
                    int m = mb + r;
                    int b = m >> 11, s = m & 2047;
                    Out[((size_t)(b * HEADS + h) * SEQ + s) * HD + dd] =
                        f2b(acc[mi][ni][r] * mul);
                }
            }
        }
    }
}

// ---------------- fused attention (key-split waves, 32-q blocks, tree epilogue) --
// Block = 32 q rows, 4 waves. Wave w owns KEYS 16w..16w+15 of every 64-key tile
// vs ALL 32 q. Grid 64x24 = 1536 blocks; LDS 33.3KB -> 4 resident blocks/CU =
// 16 waves/CU (vs 12 before). Fixed-max softmax: partials purely additive ->
// cross-wave TREE combine once per block (2 rounds, 16KB buffer).
// qw: [B,H,S,64] bf16 pre-scaled by 0.125*log2e; kw: [B,H,S,64]; vt: [B,H,64,S]
__global__ __launch_bounds__(256, 4) void attn(
    const u16* __restrict__ qw, const u16* __restrict__ kw, const u16* __restrict__ vt,
    const float* __restrict__ v_mask, const float* __restrict__ q_mask,
    float* __restrict__ out) {
    // loop phase:  Ks[2] 16KB | Vs[2] 16KB | bias[2] 512B  (33,280 B)
    // epilogue:    buf 16KB (2 regions x 2 qs x [16 q][64 d]) | lred 512B
    __shared__ __align__(16) char smem[33280];

    const int tid = threadIdx.x;
    const int lane = tid & 63, w = tid >> 6;
    const int l15 = lane & 15, g = lane >> 4;
    const int w16 = w * 16;
    const int bh = blockIdx.y;
    const int b = bh / HEADS, h = bh % HEADS;
    const int q0 = blockIdx.x * 32;

    const u16* qb = qw + (size_t)bh * SEQ * HD;
    const u16* kb = kw + (size_t)bh * SEQ * HD;
    const u16* vb = vt + (size_t)bh * HD * SEQ;
    const float* vmaskb = v_mask + (size_t)b * SEQ;

    // hoist 32 q rows as B-fragments: qf[qs][kk], q = q0 + qs*16 + l15
    bf16x8 qf[2][2];
#pragma unroll
    for (int qs = 0; qs < 2; ++qs)
#pragma unroll
        for (int kk = 0; kk < 2; ++kk) {
            int row = q0 + qs * 16 + l15;
            qf[qs][kk] = *(const bf16x8*)((const char*)qb + (size_t)row * 128 + kk * 64 + (g << 4));
        }

    // accO[qs][dt][r] = partial O[q=q0+qs*16+l15][d=dt*16+4g+r] over wave's keys
    f32x4 accO[2][4] = {};
    float lpart[2] = {0.f, 0.f};

    auto stage = [&](int t, int p) {
        const int kv0 = t * 64;
#pragma unroll
        for (int i = 0; i < 2; ++i) {
            int o = (i * 4 + w) * 1024 + lane * 16;
            int row = o >> 7;
            int col = (o & 127) ^ ((row & 7) << 4);
            gld_lds16((const char*)kb + (size_t)(kv0 + row) * 128 + col,
                      smem + p * 8192 + (i * 4 + w) * 1024);
            gld_lds16((const char*)vb + (size_t)row * (SEQ * 2) + (size_t)kv0 * 2 + col,
                      smem + 16384 + p * 8192 + (i * 4 + w) * 1024);
        }
        gld_lds4(vmaskb + kv0 + lane, smem + 32768 + p * 256);
    };

    stage(0, 0);
    __syncthreads();

    for (int t = 0; t < SEQ / 64; ++t) {
        const int cur = t & 1;
        if (t + 1 < SEQ / 64) stage(t + 1, cur ^ 1);
        const char* KsC = smem + cur * 8192;
        const char* VsC = smem + 16384 + cur * 8192;
        const float* biasC = (const float*)(smem + 32768 + cur * 256);

        // ---- K slice fragments (A-operand): row = key = 16w+l15
        bf16x8 kf[2];
        {
            int row = w16 + l15;
#pragma unroll
            for (int kk = 0; kk < 2; ++kk)
                kf[kk] = *(const bf16x8*)(KsC + row * 128 +
                                          ((kk * 64 + (g << 4)) ^ ((row & 7) << 4)));
        }
        // ---- V slice fragments: V^T[d=dt*16+l15][key=16w+4g..+3]
        s16x4 vvf[4];
#pragma unroll
        for (int dt = 0; dt < 4; ++dt) {
            int row = dt * 16 + l15;
            vvf[dt] = *(const s16x4*)(VsC + row * 128 +
                                      ((w16 * 2 + g * 8) ^ ((row & 7) << 4)));
        }
        // ---- bias for wave's keys 16w+4g..+3 (log2 domain; exact 0 when v==1)
        f32x4 vm = *(const f32x4*)(biasC + w16 + 4 * g);
        f32x4 bbv;
#pragma unroll
        for (int r = 0; r < 4; ++r)
            bbv[r] = fmaf(vm[r], 1.442695e10f, -1.442695e10f);

        // ---- S^T slice = K_w Q^T (4 MFMA): sc[qs][r]=S[key=16w+4g+r][q=qs*16+l15]
        f32x4 sc[2] = {};
#pragma unroll
        for (int kk = 0; kk < 2; ++kk)
#pragma unroll
            for (int qs = 0; qs < 2; ++qs)
                sc[qs] = __builtin_amdgcn_mfma_f32_16x16x32_bf16(
                    kf[kk], qf[qs][kk], sc[qs], 0, 0, 0);

        // ---- fixed-max softmax on the slice; P stays in registers
        s16x4 pb[2];
#pragma unroll
        for (int qs = 0; qs < 2; ++qs) {
            float ls = 0.f;
#pragma unroll
            for (int r = 0; r < 4; ++r) {
                float p = __builtin_amdgcn_exp2f(sc[qs][r] + bbv[r]);
                ls += p;
                pb[qs][r] = (short)f2b(p);
            }
            lpart[qs] += ls;
        }

        // ---- O^T partial += V_w^T P_w^T (8 x K=16 MFMA), all operands in regs
#pragma unroll
        for (int qs = 0; qs < 2; ++qs)
#pragma unroll
            for (int dt = 0; dt < 4; ++dt)
                accO[qs][dt] = __builtin_amdgcn_mfma_f32_16x16x16bf16_1k(
                    vvf[dt], pb[qs], accO[qs][dt], 0, 0, 0);

        __syncthreads();
    }

    // ---- epilogue: cross-wave additive TREE combine (2 rounds, 16KB)
    float* buf  = (float*)smem;                  // [region(2)][qs(2)][16 q][64 d]
    float* lred = (float*)(smem + 16384);        // [w][qs][16]

#pragma unroll
    for (int qs = 0; qs < 2; ++qs) {
        float v = lpart[qs];
        v += __shfl_xor(v, 16);
        v += __shfl_xor(v, 32);
        if (g == 0) lred[(w * 2 + qs) * 16 + l15] = v;
    }

    // phase 1: waves 2,3 publish their partials
    if (w >= 2) {
#pragma unroll
        for (int qs = 0; qs < 2; ++qs) {
            float* slot = buf + (w - 2) * 2048 + qs * 1024 + l15 * 64;
#pragma unroll
            for (int dt = 0; dt < 4; ++dt)
                *(f32x4*)(slot + dt * 16 + 4 * g) = accO[qs][dt];
        }
    }
    __syncthreads();
    // phase 2: wave 0 += wave 2; wave 1 += wave 3; wave 1 republishes its sum
    if (w < 2) {
#pragma unroll
        for (int qs = 0; qs < 2; ++qs) {
            const float* slot = buf + w * 2048 + qs * 1024 + l15 * 64;
#pragma unroll
            for (int dt = 0; dt < 4; ++dt)
                accO[qs][dt] += *(const f32x4*)(slot + dt * 16 + 4 * g);
        }
    }
    if (w == 1) {
#pragma unroll
        for (int qs = 0; qs < 2; ++qs) {
            float* slot = buf + 2048 + qs * 1024 + l15 * 64;
#pragma unroll
            for (int dt = 0; dt < 4; ++dt)
                *(f32x4*)(slot + dt * 16 + 4 * g) = accO[qs][dt];
        }
    }
    __syncthreads();
    // phase 3: wave 0 finalizes all 32 q rows
    if (w == 0) {
#pragma unroll
        for (int qs = 0; qs < 2; ++qs) {
            const float* slot = buf + 2048 + qs * 1024 + l15 * 64;
            f32x4 o4[4];
#pragma unroll
            for (int dt = 0; dt < 4; ++dt)
                o4[dt] = accO[qs][dt] + *(const f32x4*)(slot + dt * 16 + 4 * g);
            float ltot = lred[(0 * 2 + qs) * 16 + l15] + lred[(1 * 2 + qs) * 16 + l15] +
                         lred[(2 * 2 + qs) * 16 + l15] + lred[(3 * 2 + qs) * 16 + l15];
            int qrow = q0 + qs * 16 + l15;
            float qm = q_mask[(size_t)b * SEQ + qrow];
            float inv = (ltot > 0.f) ? qm / ltot : 0.f;
#pragma unroll
            for (int dt = 0; dt < 4; ++dt)
                *(f32x4*)(&out[((size_t)b * SEQ + qrow) * 768 + h * HD + dt * 16 + 4 * g]) =
                    o4[dt] * inv;
        }
    }
}

extern "C" void kernel_launch(void* const* d_in, const int* in_sizes, int n_in,
                              void* d_out, int out_size, void* d_ws, size_t ws_size,
                              hipStream_t stream) {
    const float* q      = (const float*)d_in[0];
    const float* k      = (const float*)d_in[1];
    const float* v      = (const float*)d_in[2];
    const float* vmask  = (const float*)d_in[3];
    const float* qmask  = (const float*)d_in[4];
    const float* Wq     = (const float*)d_in[5];
    const float* Wk     = (const float*)d_in[6];
    const float* Wv     = (const float*)d_in[7];
    float* out = (float*)d_out;

    u16* Xq  = (u16*)d_ws;
    u16* Xk  = Xq + (size_t)BS * DMODEL;
    u16* Xv  = Xk + (size_t)BS * DMODEL;
    u16* WTq = Xv + (size_t)BS * DMODEL;
    u16* WTk = WTq + (size_t)DMODEL * DMODEL;
    u16* WTv = WTk + (size_t)DMODEL * DMODEL;
    u16* qwp = WTv + (size_t)DMODEL * DMODEL;
    u16* kwp = qwp + (size_t)BATCH * HEADS * SEQ * HD;
    u16* vtp = kwp + (size_t)BATCH * HEADS * SEQ * HD;

    cvt_x<<<dim3(BS * DMODEL / 8 / 256, 1, 3), 256, 0, stream>>>(q, k, v, Xq, Xk, Xv);
    cvt_wt<<<dim3(DMODEL / 32, DMODEL / 32, 3), dim3(32, 8), 0, stream>>>(
        Wq, Wk, Wv, WTq, WTk, WTv);
    proj_gemm<<<dim3(BS / 128, DMODEL / 128, 3), 256, 0, stream>>>(
        Xq, Xk, Xv, WTq, WTk, WTv, qwp, kwp, vtp);
    attn<<<dim3(SEQ / 32, BATCH * HEADS), 256, 0, stream>>>(
        qwp, kwp, vtp, vmask, qmask, out);
}

// Round 16
// 86.947 us; speedup vs baseline: 1.1462x; 1.1462x over previous
//
#include <hip/hip_runtime.h>
#include <stdint.h>

#define HEADS 12
#define DMODEL 768
#define BATCH 2
#define SEQ 2048
#define BS (BATCH * SEQ)
#define HD 64

typedef float f32x4 __attribute__((ext_vector_type(4)));
typedef __bf16 bf16x8 __attribute__((ext_vector_type(8)));
typedef short s16x4 __attribute__((ext_vector_type(4)));
typedef unsigned short u16;
typedef u16 u16x8 __attribute__((ext_vector_type(8)));
typedef u16 u16x4 __attribute__((ext_vector_type(4)));

__device__ __forceinline__ u16 f2b(float f) {
    return __builtin_bit_cast(u16, (__bf16)f);
}

__device__ __forceinline__ void gld_lds16(const void* g, void* l) {
    __builtin_amdgcn_global_load_lds(
        (__attribute__((address_space(1))) void*)(g),
        (__attribute__((address_space(3))) void*)(l), 16, 0, 0);
}
__device__ __forceinline__ void gld_lds4(const void* g, void* l) {
    __builtin_amdgcn_global_load_lds(
        (__attribute__((address_space(1))) void*)(g),
        (__attribute__((address_space(3))) void*)(l), 4, 0, 0);
}

// ---------------- prep: fp32 -> bf16 (vectorized) ----------------
__global__ __launch_bounds__(256) void cvt_x(
    const float* __restrict__ q, const float* __restrict__ k, const float* __restrict__ v,
    u16* __restrict__ xq, u16* __restrict__ xk, u16* __restrict__ xv) {
    int z = blockIdx.z;
    const float* s = (z == 0) ? q : (z == 1) ? k : v;
    u16* d = (z == 0) ? xq : (z == 1) ? xk : xv;
    size_t i = (size_t)blockIdx.x * blockDim.x + threadIdx.x;
    const float4* s4 = (const float4*)s;
    float4 a = s4[2 * i], b = s4[2 * i + 1];
    u16x8 o;
    o[0] = f2b(a.x); o[1] = f2b(a.y); o[2] = f2b(a.z); o[3] = f2b(a.w);
    o[4] = f2b(b.x); o[5] = f2b(b.y); o[6] = f2b(b.z); o[7] = f2b(b.w);
    *(u16x8*)(d + 8 * i) = o;
}

// ---------------- prep: W -> W^T bf16 ----------------
__global__ void cvt_wt(const float* __restrict__ wq, const float* __restrict__ wk,
                       const float* __restrict__ wv,
                       u16* __restrict__ tq, u16* __restrict__ tk, u16* __restrict__ tv) {
    int z = blockIdx.z;
    const float* w = (z == 0) ? wq : (z == 1) ? wk : wv;
    u16* t = (z == 0) ? tq : (z == 1) ? tk : tv;
    __shared__ float tile[32][33];
    int tx = threadIdx.x, ty = threadIdx.y;
    int kb = blockIdx.y * 32, nb = blockIdx.x * 32;
    for (int r = 0; r < 32; r += 8)
        tile[ty + r][tx] = w[(size_t)(kb + ty + r) * DMODEL + nb + tx];
    __syncthreads();
    for (int r = 0; r < 32; r += 8)
        t[(size_t)(nb + ty + r) * DMODEL + kb + tx] = f2b(tile[tx][ty + r]);
}

// ---------------- projection GEMM: C[m][n] = X[m][k] * W[k][n] ----------------
// Round-16: 128x96 tile -> grid 32x8x3 = 768 blocks = EXACTLY 3/CU (balanced;
// the 576-block 2.25/CU grid left a 1/3 idle tail). LDS 28KB, bounds(256,3).
// z=0 -> qw [B,H,S,64] PRE-SCALED by 0.125*log2(e); z=1 -> kw [B,H,S,64];
// z=2 -> vt [B,H,64,S] via swapped-operand MFMA (C^T fragments, coalesced stores)
__global__ __launch_bounds__(256, 3) void proj_gemm(
    const u16* __restrict__ xq, const u16* __restrict__ xk, const u16* __restrict__ xv,
    const u16* __restrict__ tq, const u16* __restrict__ tk, const u16* __restrict__ tv,
    u16* __restrict__ oq, u16* __restrict__ ok, u16* __restrict__ ov) {
    const int z = blockIdx.z;
    const u16* X  = (z == 0) ? xq : (z == 1) ? xk : xv;
    const u16* WT = (z == 0) ? tq : (z == 1) ? tk : tv;
    u16* Out      = (z == 0) ? oq : (z == 1) ? ok : ov;

    __shared__ u16 As[128 * 64];   // 16 KB
    __shared__ u16 Bs[96 * 64];    // 12 KB

    const int tid = threadIdx.x;
    const int lane = tid & 63, w = tid >> 6;
    const int wm = w >> 1, wn = w & 1;          // wave tile: 64 m x 48 n
    const int m0 = blockIdx.x * 128, n0 = blockIdx.y * 96;

    f32x4 acc[4][3] = {};

    for (int kt = 0; kt < DMODEL / 64; ++kt) {
#pragma unroll
        for (int p = 0; p < 4; ++p) {
            int o = (p * 4 + w) * 1024 + lane * 16;
            int row = o >> 7;
            int col = (o & 127) ^ ((row & 7) << 4);
            gld_lds16((const char*)X + (size_t)(m0 + row) * (DMODEL * 2) + kt * 128 + col,
                      (char*)As + (p * 4 + w) * 1024);
        }
#pragma unroll
        for (int p = 0; p < 3; ++p) {
            int o = (p * 4 + w) * 1024 + lane * 16;
            int row = o >> 7;
            int col = (o & 127) ^ ((row & 7) << 4);
            gld_lds16((const char*)WT + (size_t)(n0 + row) * (DMODEL * 2) + kt * 128 + col,
                      (char*)Bs + (p * 4 + w) * 1024);
        }
        __syncthreads();
#pragma unroll
        for (int kk = 0; kk < 2; ++kk) {
            bf16x8 af[4], bfr[3];
#pragma unroll
            for (int mi = 0; mi < 4; ++mi) {
                int row = wm * 64 + mi * 16 + (lane & 15);
                int col = (kk * 64 + ((lane >> 4) << 4)) ^ ((row & 7) << 4);
                af[mi] = *(const bf16x8*)((const char*)As + row * 128 + col);
            }
#pragma unroll
            for (int ni = 0; ni < 3; ++ni) {
                int row = wn * 48 + ni * 16 + (lane & 15);
                int col = (kk * 64 + ((lane >> 4) << 4)) ^ ((row & 7) << 4);
                bfr[ni] = *(const bf16x8*)((const char*)Bs + row * 128 + col);
            }
            if (z == 2) {
#pragma unroll
                for (int mi = 0; mi < 4; ++mi)
#pragma unroll
                    for (int ni = 0; ni < 3; ++ni)
                        acc[mi][ni] = __builtin_amdgcn_mfma_f32_16x16x32_bf16(
                            bfr[ni], af[mi], acc[mi][ni], 0, 0, 0);   // C^T fragments
            } else {
#pragma unroll
                for (int mi = 0; mi < 4; ++mi)
#pragma unroll
                    for (int ni = 0; ni < 3; ++ni)
                        acc[mi][ni] = __builtin_amdgcn_mfma_f32_16x16x32_bf16(
                            af[mi], bfr[ni], acc[mi][ni], 0, 0, 0);
            }
        }
        __syncthreads();
    }

    if (z == 2) {
        // acc[mi][ni]: row=(lane>>4)*4+r -> n (=h,dd), col=lane&15 -> m (=b,s)
        const int m = m0 + wm * 64 + (tid & 15);
        const int b = m >> 11;
#pragma unroll
        for (int mi = 0; mi < 4; ++mi) {
            int s = ((m + mi * 16) & 2047);
#pragma unroll
            for (int ni = 0; ni < 3; ++ni) {
                int nb2 = n0 + wn * 48 + ni * 16 + (((tid & 63) >> 4) << 2);
#pragma unroll
                for (int r = 0; r < 4; ++r) {
                    int n = nb2 + r;
                    int h = n >> 6, dd = n & 63;
                    Out[((size_t)(b * HEADS + h) * HD + dd) * SEQ + s] =
                        f2b(acc[mi][ni][r]);
                }
            }
        }
    } else {
        const float mul = (z == 0) ? 0.125f * 1.44269504f : 1.0f;
#pragma unroll
        for (int mi = 0; mi < 4; ++mi) {
            int mb = m0 + wm * 64 + mi * 16 + (((tid & 63) >> 4) << 2);
#pragma unroll
            for (int ni = 0; ni < 3; ++ni) {
                int n = n0 + wn * 48 + ni * 16 + (tid & 15);
                int h = n >> 6, dd = n & 63;
#pragma unroll
                for (int r = 0; r < 4; ++r) {
                    int m = mb + r;
                    int b = m >> 11, s = m & 2047;
                    Out[((size_t)(b * HEADS + h) * SEQ + s) * HD + dd] =
                        f2b(acc[mi][ni][r] * mul);
                }
            }
        }
    }
}

// ---------------- fused attention (round-13/14 proven; byte-identical) ----------
// Block = 64 q rows, 4 waves. Wave w owns KEYS 16w..16w+15 of every tile and
// computes them against ALL 64 q (Q hoisted x4). Fixed-max softmax makes l/O
// partials purely additive -> cross-wave combine ONCE per block (LDS epilogue).
// Per-wave-tile LDS reads: 2 b128 (K slice) + 4 b64 (V slice).
// qw: [B,H,S,64] bf16 pre-scaled by 0.125*log2e; kw: [B,H,S,64]; vt: [B,H,64,S]
__global__ __launch_bounds__(256, 3) void attn(
    const u16* __restrict__ qw, const u16* __restrict__ kw, const u16* __restrict__ vt,
    const float* __restrict__ v_mask, const float* __restrict__ q_mask,
    float* __restrict__ out) {
    // loop phase:  Ks[2] 16KB | Vs[2] 16KB | bias[2] 512B   (33,280 B)
    // epilogue:    buf 48KB ([4 qs][3 j][16 q][64 d] f32) | lred 1KB
    __shared__ __align__(16) char smem[50176];

    const int tid = threadIdx.x;
    const int lane = tid & 63, w = tid >> 6;
    const int l15 = lane & 15, g = lane >> 4;
    const int w16 = w * 16;
    const int bh = blockIdx.y;
    const int b = bh / HEADS, h = bh % HEADS;
    const int q0 = blockIdx.x * 64;

    const u16* qb = qw + (size_t)bh * SEQ * HD;
    const u16* kb = kw + (size_t)bh * SEQ * HD;
    const u16* vb = vt + (size_t)bh * HD * SEQ;
    const float* vmaskb = v_mask + (size_t)b * SEQ;

    // hoist ALL 64 q rows as B-fragments: qf[qs][kk], q = q0 + qs*16 + l15
    bf16x8 qf[4][2];
#pragma unroll
    for (int qs = 0; qs < 4; ++qs)
#pragma unroll
        for (int kk = 0; kk < 2; ++kk) {
            int row = q0 + qs * 16 + l15;
            qf[qs][kk] = *(const bf16x8*)((const char*)qb + (size_t)row * 128 + kk * 64 + (g << 4));
        }

    // accO[qs][dt][r] = partial O[q=q0+qs*16+l15][d=dt*16+4g+r] over wave's keys
    f32x4 accO[4][4] = {};
    float lpart[4] = {0.f, 0.f, 0.f, 0.f};

    auto stage = [&](int t, int p) {
        const int kv0 = t * 64;
#pragma unroll
        for (int i = 0; i < 2; ++i) {
            int o = (i * 4 + w) * 1024 + lane * 16;
            int row = o >> 7;
            int col = (o & 127) ^ ((row & 7) << 4);
            gld_lds16((const char*)kb + (size_t)(kv0 + row) * 128 + col,
                      smem + p * 8192 + (i * 4 + w) * 1024);
            gld_lds16((const char*)vb + (size_t)row * (SEQ * 2) + (size_t)kv0 * 2 + col,
                      smem + 16384 + p * 8192 + (i * 4 + w) * 1024);
        }
        gld_lds4(vmaskb + kv0 + lane, smem + 32768 + p * 256);
    };

    stage(0, 0);
    __syncthreads();

    for (int t = 0; t < SEQ / 64; ++t) {
        const int cur = t & 1;
        if (t + 1 < SEQ / 64) stage(t + 1, cur ^ 1);
        const char* KsC = smem + cur * 8192;
        const char* VsC = smem + 16384 + cur * 8192;
        const float* biasC = (const float*)(smem + 32768 + cur * 256);

        // ---- K slice fragments (A-operand): row = key = 16w+l15
        bf16x8 kf[2];
        {
            int row = w16 + l15;
#pragma unroll
            for (int kk = 0; kk < 2; ++kk)
                kf[kk] = *(const bf16x8*)(KsC + row * 128 +
                                          ((kk * 64 + (g << 4)) ^ ((row & 7) << 4)));
        }
        // ---- V slice fragments: V^T[d=dt*16+l15][key=16w+4g..+3] (issued early)
        s16x4 vvf[4];
#pragma unroll
        for (int dt = 0; dt < 4; ++dt) {
            int row = dt * 16 + l15;
            vvf[dt] = *(const s16x4*)(VsC + row * 128 +
                                      ((w16 * 2 + g * 8) ^ ((row & 7) << 4)));
        }
        // ---- bias for wave's keys 16w+4g..+3 (log2 domain; exact 0 when v==1)
        f32x4 vm = *(const f32x4*)(biasC + w16 + 4 * g);
        f32x4 bbv;
#pragma unroll
        for (int r = 0; r < 4; ++r)
            bbv[r] = fmaf(vm[r], 1.442695e10f, -1.442695e10f);

        // ---- S^T slice = K_w Q^T (8 MFMA): sc[qs][r]=S[key=16w+4g+r][q=qs*16+l15]
        f32x4 sc[4] = {};
#pragma unroll
        for (int kk = 0; kk < 2; ++kk)
#pragma unroll
            for (int qs = 0; qs < 4; ++qs)
                sc[qs] = __builtin_amdgcn_mfma_f32_16x16x32_bf16(
                    kf[kk], qf[qs][kk], sc[qs], 0, 0, 0);

        // ---- fixed-max softmax on the slice; P stays in registers
        s16x4 pb[4];
#pragma unroll
        for (int qs = 0; qs < 4; ++qs) {
            float ls = 0.f;
#pragma unroll
            for (int r = 0; r < 4; ++r) {
                float p = __builtin_amdgcn_exp2f(sc[qs][r] + bbv[r]);
                ls += p;
                pb[qs][r] = (short)f2b(p);
            }
            lpart[qs] += ls;
        }

        // ---- O^T partial += V_w^T P_w^T (16 x K=16 MFMA), all operands in regs
#pragma unroll
        for (int qs = 0; qs < 4; ++qs)
#pragma unroll
            for (int dt = 0; dt < 4; ++dt)
                accO[qs][dt] = __builtin_amdgcn_mfma_f32_16x16x16bf16_1k(
                    vvf[dt], pb[qs], accO[qs][dt], 0, 0, 0);

        __syncthreads();
    }

    // ---- epilogue: cross-wave additive combine (once per block)
    float* buf  = (float*)smem;                  // [qs][j][16 q][64 d]
    float* lred = (float*)(smem + 49152);        // [w][qs][16]

    float lq[4];
#pragma unroll
    for (int qs = 0; qs < 4; ++qs) {
        float v = lpart[qs];
        v += __shfl_xor(v, 16);
        v += __shfl_xor(v, 32);
        lq[qs] = v;
    }
    if (g == 0)
#pragma unroll
        for (int qs = 0; qs < 4; ++qs)
            lred[(w * 4 + qs) * 16 + l15] = lq[qs];

    // rule #20: copy own slab with STATIC indices (runtime condition only)
    f32x4 own[4] = {};
#pragma unroll
    for (int qs = 0; qs < 4; ++qs)
        if (qs == w) {
#pragma unroll
            for (int dt = 0; dt < 4; ++dt) own[dt] = accO[qs][dt];
        }

#pragma unroll
    for (int qs = 0; qs < 4; ++qs) {
        if (qs == w) continue;                   // runtime branch, static indices
        int j = (w < qs) ? w : w - 1;
        float* slot = buf + ((qs * 3 + j) * 16 + l15) * 64;
#pragma unroll
        for (int dt = 0; dt < 4; ++dt)
            *(f32x4*)(slot + dt * 16 + 4 * g) = accO[qs][dt];
    }
    __syncthreads();

    {
#pragma unroll
        for (int j = 0; j < 3; ++j) {
            const float* slot = buf + ((w * 3 + j) * 16 + l15) * 64;  // LDS addr: runtime w OK
#pragma unroll
            for (int dt = 0; dt < 4; ++dt)
                own[dt] += *(const f32x4*)(slot + dt * 16 + 4 * g);
        }
        float ltot = lred[(0 * 4 + w) * 16 + l15] + lred[(1 * 4 + w) * 16 + l15] +
                     lred[(2 * 4 + w) * 16 + l15] + lred[(3 * 4 + w) * 16 + l15];
        int qrow = q0 + w16 + l15;
        float qm = q_mask[(size_t)b * SEQ + qrow];
        float inv = (ltot > 0.f) ? qm / ltot : 0.f;
#pragma unroll
        for (int dt = 0; dt < 4; ++dt) {
            f32x4 o = own[dt] * inv;
            *(f32x4*)(&out[((size_t)b * SEQ + qrow) * 768 + h * HD + dt * 16 + 4 * g]) = o;
        }
    }
}

extern "C" void kernel_launch(void* const* d_in, const int* in_sizes, int n_in,
                              void* d_out, int out_size, void* d_ws, size_t ws_size,
                              hipStream_t stream) {
    const float* q      = (const float*)d_in[0];
    const float* k      = (const float*)d_in[1];
    const float* v      = (const float*)d_in[2];
    const float* vmask  = (const float*)d_in[3];
    const float* qmask  = (const float*)d_in[4];
    const float* Wq     = (const float*)d_in[5];
    const float* Wk     = (const float*)d_in[6];
    const float* Wv     = (const float*)d_in[7];
    float* out = (float*)d_out;

    u16* Xq  = (u16*)d_ws;
    u16* Xk  = Xq + (size_t)BS * DMODEL;
    u16* Xv  = Xk + (size_t)BS * DMODEL;
    u16* WTq = Xv + (size_t)BS * DMODEL;
    u16* WTk = WTq + (size_t)DMODEL * DMODEL;
    u16* WTv = WTk + (size_t)DMODEL * DMODEL;
    u16* qwp = WTv + (size_t)DMODEL * DMODEL;
    u16* kwp = qwp + (size_t)BATCH * HEADS * SEQ * HD;
    u16* vtp = kwp + (size_t)BATCH * HEADS * SEQ * HD;

    cvt_x<<<dim3(BS * DMODEL / 8 / 256, 1, 3), 256, 0, stream>>>(q, k, v, Xq, Xk, Xv);
    cvt_wt<<<dim3(DMODEL / 32, DMODEL / 32, 3), dim3(32, 8), 0, stream>>>(
        Wq, Wk, Wv, WTq, WTk, WTv);
    proj_gemm<<<dim3(BS / 128, DMODEL / 96, 3), 256, 0, stream>>>(
        Xq, Xk, Xv, WTq, WTk, WTv, qwp, kwp, vtp);
    attn<<<dim3(SEQ / 64, BATCH * HEADS), 256, 0, stream>>>(
        qwp, kwp, vtp, vmask, qmask, out);
}